// Round 6
// baseline (953.029 us; speedup 1.0000x reference)
//
#include <hip/hip_runtime.h>
#include <hip/hip_bf16.h>
#include <math.h>

#define BB 2
#define NN 512
#define CS 384
#define CZ 128
#define HH 12
#define CATW 2112

#define W_L_CONST 0.57735026919f
#define W_C_HALF 0.11785113019f
#define INV_SQRT_D 0.25f
#define LGP 516   // padded row stride for lg[h][*]

// ---------------- Kernel 1: projections + rigid apply (2 tokens/block) ----
// 5 tasks/thread batched in one c-loop: s_row read ONCE per c4 as b128
// broadcast (shared by all tasks) -> DS inst 3456 b32 -> 192 b128 per thread.
__global__ __attribute__((amdgpu_waves_per_eu(2, 4)))
void k_proj(const float* __restrict__ s_i,
            const float* __restrict__ rots,
            const float* __restrict__ trans,
            const float* __restrict__ wq,
            const float* __restrict__ wk,
            const float* __restrict__ wv,
            const float* __restrict__ wqp,
            const float* __restrict__ wkp,
            const float* __restrict__ wvp,
            float* __restrict__ qw, float* __restrict__ kw,
            float* __restrict__ vw, float* __restrict__ tqw,
            float* __restrict__ tkw, float* __restrict__ tvw) {
  int t0 = blockIdx.x * 2;
  __shared__ float s_row[2][CS];
  __shared__ float praw[2][576];
  __shared__ float R[2][9], T[2][3];
  int tid = threadIdx.x;
  for (int idx = tid; idx < 2 * CS; idx += 256) {
    int tok = idx / CS, c = idx % CS;
    s_row[tok][c] = s_i[(size_t)(t0 + tok) * CS + c];
  }
  if (tid < 18) R[tid / 9][tid % 9] = rots[t0 * 9 + tid];
  if (tid < 6) T[tid / 3][tid % 3] = trans[t0 * 3 + tid];
  __syncthreads();

  // 5 tasks per thread; task 4 duplicated across half-blocks (benign same-value
  // double write to praw).
  int fa[5];
  fa[0] = tid; fa[1] = tid + 256; fa[2] = tid + 512; fa[3] = tid + 768;
  fa[4] = 1024 + (tid & 127);
  const float* wp[5];
  int st[5];
  #pragma unroll
  for (int t = 0; t < 5; t++) {
    int f = fa[t];
    if (f < 576) {
      int sel = f / 192, r = f % 192;
      wp[t] = ((sel == 0) ? wq : (sel == 1) ? wk : wv) + r;
      st[t] = 192;
    } else {
      int g = f - 576;
      if (g < 144)      { wp[t] = wqp + g;         st[t] = 144; }
      else if (g < 288) { wp[t] = wkp + (g - 144); st[t] = 144; }
      else              { wp[t] = wvp + (g - 288); st[t] = 288; }
    }
  }
  float acc[5][2];
  #pragma unroll
  for (int t = 0; t < 5; t++) { acc[t][0] = 0.f; acc[t][1] = 0.f; }

  for (int c4 = 0; c4 < 96; c4++) {
    float4 s0 = *(const float4*)&s_row[0][c4 * 4];
    float4 s1 = *(const float4*)&s_row[1][c4 * 4];
    #pragma unroll
    for (int t = 0; t < 5; t++) {
      const float* p = wp[t] + (size_t)(c4 * 4) * st[t];
      float w0 = p[0];
      float w1 = p[st[t]];
      float w2 = p[2 * st[t]];
      float w3 = p[3 * st[t]];
      acc[t][0] = fmaf(s0.x, w0, acc[t][0]);
      acc[t][0] = fmaf(s0.y, w1, acc[t][0]);
      acc[t][0] = fmaf(s0.z, w2, acc[t][0]);
      acc[t][0] = fmaf(s0.w, w3, acc[t][0]);
      acc[t][1] = fmaf(s1.x, w0, acc[t][1]);
      acc[t][1] = fmaf(s1.y, w1, acc[t][1]);
      acc[t][1] = fmaf(s1.z, w2, acc[t][1]);
      acc[t][1] = fmaf(s1.w, w3, acc[t][1]);
    }
  }

  #pragma unroll
  for (int t = 0; t < 5; t++) {
    int f = fa[t];
    if (f < 576) {
      int sel = f / 192, r = f % 192;
      float* dst = (sel == 0) ? qw : (sel == 1) ? kw : vw;
      dst[(size_t)(t0 + 0) * 192 + r] = acc[t][0];
      dst[(size_t)(t0 + 1) * 192 + r] = acc[t][1];
    } else {
      int g = f - 576;
      praw[0][g] = acc[t][0];
      praw[1][g] = acc[t][1];
    }
  }
  __syncthreads();
  for (int idx = tid; idx < 1152; idx += 256) {
    int tok = idx / 576, f = idx % 576;
    int base, r;
    float* dst;
    if (f < 144)      { r = f;       base = 0;   dst = tqw + (size_t)(t0 + tok) * 144; }
    else if (f < 288) { r = f - 144; base = 144; dst = tkw + (size_t)(t0 + tok) * 144; }
    else              { r = f - 288; base = 288; dst = tvw + (size_t)(t0 + tok) * 288; }
    int hp = r / 3, x = r % 3;
    float v0 = praw[tok][base + hp * 3 + 0];
    float v1 = praw[tok][base + hp * 3 + 1];
    float v2 = praw[tok][base + hp * 3 + 2];
    dst[r] = R[tok][x * 3 + 0] * v0 + R[tok][x * 3 + 1] * v1 + R[tok][x * 3 + 2] * v2 + T[tok][x];
  }
}

// ---------------- Kernel 2: pair bias GEMM (z @ wb), register-cached ------
// No LDS. 32-lane group = 4 head-groups x 8 c-segments; each lane holds
// wb for (3 heads x 16 c) in 48 VGPRs. z read coalesced float4, 2 rows
// batched; 3-step shfl_xor reduce over the 8 c-lanes; float2 stores.
#define BQ(v, q, sx0, sx1, sx2)                                        \
  sx0 = fmaf(v.x, w[(q)*4 + 0][0], sx0);                               \
  sx1 = fmaf(v.x, w[(q)*4 + 0][1], sx1);                               \
  sx2 = fmaf(v.x, w[(q)*4 + 0][2], sx2);                               \
  sx0 = fmaf(v.y, w[(q)*4 + 1][0], sx0);                               \
  sx1 = fmaf(v.y, w[(q)*4 + 1][1], sx1);                               \
  sx2 = fmaf(v.y, w[(q)*4 + 1][2], sx2);                               \
  sx0 = fmaf(v.z, w[(q)*4 + 2][0], sx0);                               \
  sx1 = fmaf(v.z, w[(q)*4 + 2][1], sx1);                               \
  sx2 = fmaf(v.z, w[(q)*4 + 2][2], sx2);                               \
  sx0 = fmaf(v.w, w[(q)*4 + 3][0], sx0);                               \
  sx1 = fmaf(v.w, w[(q)*4 + 3][1], sx1);                               \
  sx2 = fmaf(v.w, w[(q)*4 + 3][2], sx2);

__global__ __attribute__((amdgpu_waves_per_eu(2, 4)))
void k_bias(const float* __restrict__ z,
            const float* __restrict__ wb,
            float* __restrict__ bw) {
  int tid = threadIdx.x;
  int l32 = tid & 31;
  int grp = tid >> 5;          // 0..7: 32-lane group in block
  int hg = l32 >> 3;           // 0..3: head group (3 heads each)
  int cs = l32 & 7;            // 0..7: c segment (16 c each)

  float w[16][3];
  #pragma unroll
  for (int cc = 0; cc < 16; cc++) {
    const float* p = wb + (size_t)(cs * 16 + cc) * HH + hg * 3;
    w[cc][0] = p[0]; w[cc][1] = p[1]; w[cc][2] = p[2];
  }

  int r0 = blockIdx.x * 256 + grp * 32;   // block covers 256 aligned rows
  int bi = r0 >> 9;                       // constant within block
  for (int rr = 0; rr < 32; rr += 2) {
    const float* zA = z + (size_t)(r0 + rr) * CZ + cs * 16;
    const float* zB = zA + CZ;
    float4 a0 = ((const float4*)zA)[0];
    float4 a1 = ((const float4*)zA)[1];
    float4 a2 = ((const float4*)zA)[2];
    float4 a3 = ((const float4*)zA)[3];
    float4 b0 = ((const float4*)zB)[0];
    float4 b1 = ((const float4*)zB)[1];
    float4 b2 = ((const float4*)zB)[2];
    float4 b3 = ((const float4*)zB)[3];
    float sA0 = 0.f, sA1 = 0.f, sA2 = 0.f;
    float sB0 = 0.f, sB1 = 0.f, sB2 = 0.f;
    BQ(a0, 0, sA0, sA1, sA2)
    BQ(a1, 1, sA0, sA1, sA2)
    BQ(a2, 2, sA0, sA1, sA2)
    BQ(a3, 3, sA0, sA1, sA2)
    BQ(b0, 0, sB0, sB1, sB2)
    BQ(b1, 1, sB0, sB1, sB2)
    BQ(b2, 2, sB0, sB1, sB2)
    BQ(b3, 3, sB0, sB1, sB2)
    // reduce over cs lanes (lane bits 0..2)
    sA0 += __shfl_xor(sA0, 1, 64); sA0 += __shfl_xor(sA0, 2, 64); sA0 += __shfl_xor(sA0, 4, 64);
    sA1 += __shfl_xor(sA1, 1, 64); sA1 += __shfl_xor(sA1, 2, 64); sA1 += __shfl_xor(sA1, 4, 64);
    sA2 += __shfl_xor(sA2, 1, 64); sA2 += __shfl_xor(sA2, 2, 64); sA2 += __shfl_xor(sA2, 4, 64);
    sB0 += __shfl_xor(sB0, 1, 64); sB0 += __shfl_xor(sB0, 2, 64); sB0 += __shfl_xor(sB0, 4, 64);
    sB1 += __shfl_xor(sB1, 1, 64); sB1 += __shfl_xor(sB1, 2, 64); sB1 += __shfl_xor(sB1, 4, 64);
    sB2 += __shfl_xor(sB2, 1, 64); sB2 += __shfl_xor(sB2, 2, 64); sB2 += __shfl_xor(sB2, 4, 64);
    if (cs == 0) {
      int jA = (r0 + rr) & 511;           // even -> 8B-aligned float2 stores
      float* d = bw + ((size_t)bi * HH + hg * 3) * NN + jA;
      *(float2*)&d[0]      = make_float2(sA0, sB0);
      *(float2*)&d[NN]     = make_float2(sA1, sB1);
      *(float2*)&d[2 * NN] = make_float2(sA2, sB2);
    }
  }
}

// ---------------- Kernel 3: fused logits+softmax+o/o_hp+o_hat ------------
// block per (b,i), 256 threads  (round-0 proven version)
__global__ void k_att(const float* __restrict__ z,
                      const float* __restrict__ qw,
                      const float* __restrict__ kw,
                      const float* __restrict__ tqw,
                      const float* __restrict__ tkw,
                      const float* __restrict__ vw,
                      const float* __restrict__ tvw,
                      const float* __restrict__ gamma,
                      const float* __restrict__ rots,
                      const float* __restrict__ trans,
                      const float* __restrict__ bw,
                      float* __restrict__ catm) {
  int bi = blockIdx.x;
  int b = bi / NN;
  __shared__ float lg[HH][LGP];         // logits -> a -> (reused) o_hat partials
  __shared__ float opart[4][480];
  __shared__ float qrow[192], tqrow[144], gam[HH];
  __shared__ float rm[HH][4], rs[HH][4];
  __shared__ float praw[288], ohp[288], R[9], T[3];
  int tid = threadIdx.x;
  int lane = tid & 63, wid = tid >> 6;

  const float* bwrow = bw + (size_t)bi * (HH * NN);
  for (int idx = tid; idx < HH * NN; idx += 256)
    lg[idx >> 9][idx & 511] = bwrow[idx];
  for (int idx = tid; idx < 192; idx += 256) qrow[idx] = qw[(size_t)bi * 192 + idx];
  if (tid < 144) tqrow[tid] = tqw[(size_t)bi * 144 + tid];
  if (tid < HH) gam[tid] = gamma[tid];
  if (tid < 9) R[tid] = rots[bi * 9 + tid];
  if (tid < 3) T[tid] = trans[bi * 3 + tid];
  __syncthreads();

  // ---- logits: 6144 tasks = 24 * 256 ----
  for (int s = 0; s < 24; s++) {
    int task = tid + s * 256;
    int j = task / 12, h = task % 12;
    const float4* kd = (const float4*)(kw + ((size_t)(b * NN + j)) * 192 + h * 16);
    float as = 0.f;
    #pragma unroll
    for (int q = 0; q < 4; q++) {
      float4 kv = kd[q];
      as += qrow[h * 16 + q * 4 + 0] * kv.x + qrow[h * 16 + q * 4 + 1] * kv.y +
            qrow[h * 16 + q * 4 + 2] * kv.z + qrow[h * 16 + q * 4 + 3] * kv.w;
    }
    const float4* td = (const float4*)(tkw + ((size_t)(b * NN + j)) * 144 + h * 12);
    float d2 = 0.f;
    #pragma unroll
    for (int q = 0; q < 3; q++) {
      float4 tv = td[q];
      float d0 = tqrow[h * 12 + q * 4 + 0] - tv.x;
      float d1 = tqrow[h * 12 + q * 4 + 1] - tv.y;
      float d2_ = tqrow[h * 12 + q * 4 + 2] - tv.z;
      float d3 = tqrow[h * 12 + q * 4 + 3] - tv.w;
      d2 += d0 * d0 + d1 * d1 + d2_ * d2_ + d3 * d3;
    }
    lg[h][j] = W_L_CONST * (as * INV_SQRT_D + lg[h][j] - W_C_HALF * gam[h] * d2);
  }
  __syncthreads();

  // ---- softmax ----
  #pragma unroll
  for (int h = 0; h < HH; h++) {
    float m = fmaxf(lg[h][tid], lg[h][tid + 256]);
    #pragma unroll
    for (int off = 32; off >= 1; off >>= 1) m = fmaxf(m, __shfl_xor(m, off, 64));
    if (lane == 0) rm[h][wid] = m;
  }
  __syncthreads();
  #pragma unroll
  for (int h = 0; h < HH; h++) {
    float mx = fmaxf(fmaxf(rm[h][0], rm[h][1]), fmaxf(rm[h][2], rm[h][3]));
    float e0 = __expf(lg[h][tid] - mx);
    float e1 = __expf(lg[h][tid + 256] - mx);
    lg[h][tid] = e0;
    lg[h][tid + 256] = e1;
    float s = e0 + e1;
    #pragma unroll
    for (int off = 32; off >= 1; off >>= 1) s += __shfl_xor(s, off, 64);
    if (lane == 0) rs[h][wid] = s;
  }
  __syncthreads();
  #pragma unroll
  for (int h = 0; h < HH; h++) {
    float inv = 1.0f / (rs[h][0] + rs[h][1] + rs[h][2] + rs[h][3]);
    lg[h][tid] *= inv;
    lg[h][tid + 256] *= inv;
  }
  __syncthreads();   // lg now holds a

  float* crow = catm + (size_t)bi * CATW;
  int j0 = wid * 128;   // this wave's j window

  // ---- o / o_hp partials: wave-split over j ----
  for (int t = lane; t < 480; t += 64) {
    const float* src;
    int h, str;
    if (t < 192) { h = t >> 4; src = vw + (size_t)b * NN * 192 + t; str = 192; }
    else { int f = t - 192; h = f / 24; src = tvw + (size_t)b * NN * 288 + f; str = 288; }
    float sum = 0.f;
    for (int jj = 0; jj < 128; jj += 4) {
      float4 av = *(const float4*)&lg[h][j0 + jj];
      sum += av.x * src[(size_t)(j0 + jj + 0) * str]
           + av.y * src[(size_t)(j0 + jj + 1) * str]
           + av.z * src[(size_t)(j0 + jj + 2) * str]
           + av.w * src[(size_t)(j0 + jj + 3) * str];
    }
    opart[wid][t] = sum;
  }
  __syncthreads();
  for (int t = tid; t < 480; t += 256) {
    float s = opart[0][t] + opart[1][t] + opart[2][t] + opart[3][t];
    if (t < 192) crow[1536 + t] = s;
    else praw[t - 192] = s;
  }
  __syncthreads();
  for (int f = tid; f < 288; f += 256) {
    int g = f / 3, x = f % 3;
    float v0 = praw[g * 3 + 0] - T[0];
    float v1 = praw[g * 3 + 1] - T[1];
    float v2 = praw[g * 3 + 2] - T[2];
    float val = R[0 * 3 + x] * v0 + R[1 * 3 + x] * v1 + R[2 * 3 + x] * v2;
    ohp[f] = val;
    crow[1728 + f] = val;
  }
  __syncthreads();
  if (tid < 96) {
    float x0 = ohp[tid * 3 + 0];
    float x1 = ohp[tid * 3 + 1];
    float x2 = ohp[tid * 3 + 2];
    crow[2016 + tid] = sqrtf(x0 * x0 + x1 * x1 + x2 * x2);
  }

  // ---- o_hat: stream z (second pass), half-wave j-split, float4 c ----
  int hw = lane >> 5, c4 = (lane & 31) * 4;
  float4 acc[HH];
  #pragma unroll
  for (int h = 0; h < HH; h++) acc[h] = make_float4(0.f, 0.f, 0.f, 0.f);
  for (int stp = 0; stp < 64; stp++) {
    int j = j0 + stp * 2 + hw;
    float4 zv = *(const float4*)(z + ((size_t)bi * NN + j) * CZ + c4);
    #pragma unroll
    for (int h = 0; h < HH; h++) {
      float a = lg[h][j];
      acc[h].x += a * zv.x;
      acc[h].y += a * zv.y;
      acc[h].z += a * zv.z;
      acc[h].w += a * zv.w;
    }
  }
  __syncthreads();   // all reads of lg complete everywhere; safe to reuse
  #pragma unroll
  for (int h = 0; h < HH; h++) {
    acc[h].x += __shfl_xor(acc[h].x, 32, 64);
    acc[h].y += __shfl_xor(acc[h].y, 32, 64);
    acc[h].z += __shfl_xor(acc[h].z, 32, 64);
    acc[h].w += __shfl_xor(acc[h].w, 32, 64);
  }
  float* pbuf = &lg[0][0];
  if (lane < 32) {
    #pragma unroll
    for (int h = 0; h < HH; h++)
      *(float4*)&pbuf[wid * 1536 + h * 128 + lane * 4] = acc[h];
  }
  __syncthreads();
  #pragma unroll
  for (int s = 0; s < 6; s++) {
    int idx = tid + s * 256;
    crow[idx] = pbuf[idx] + pbuf[1536 + idx] + pbuf[3072 + idx] + pbuf[4608 + idx];
  }
}

// ---------------- Kernel 4: output GEMM, split-K=4, 64x64, 4x4 reg tile ---
#define KCH 528
__global__ void k_gemm(const float* __restrict__ catm,
                       const float* __restrict__ wout,
                       float* __restrict__ pout) {
  __shared__ float As[16][68];   // [kk][m], padded
  __shared__ float Bs[16][64];   // [kk][n]
  int tid = threadIdx.x;
  int n0 = blockIdx.x * 64, m0 = blockIdx.y * 64, kbase = blockIdx.z * KCH;
  int tx = tid & 15, ty = tid >> 4;
  int sm = tid & 63, skk4 = tid >> 6;
  int bkk = tid >> 4, bn4 = (tid & 15) * 4;
  float acc[4][4] = {};
  for (int kt = 0; kt < KCH / 16; kt++) {
    int k0 = kbase + kt * 16;
    float4 ga = *(const float4*)(catm + (size_t)(m0 + sm) * CATW + k0 + skk4 * 4);
    float4 gb = *(const float4*)(wout + (size_t)(k0 + bkk) * 384 + n0 + bn4);
    __syncthreads();
    As[skk4 * 4 + 0][sm] = ga.x;
    As[skk4 * 4 + 1][sm] = ga.y;
    As[skk4 * 4 + 2][sm] = ga.z;
    As[skk4 * 4 + 3][sm] = ga.w;
    *(float4*)&Bs[bkk][bn4] = gb;
    __syncthreads();
    #pragma unroll
    for (int kk = 0; kk < 16; kk++) {
      float4 av = *(const float4*)&As[kk][ty * 4];
      float4 bv = *(const float4*)&Bs[kk][tx * 4];
      acc[0][0] += av.x * bv.x; acc[0][1] += av.x * bv.y; acc[0][2] += av.x * bv.z; acc[0][3] += av.x * bv.w;
      acc[1][0] += av.y * bv.x; acc[1][1] += av.y * bv.y; acc[1][2] += av.y * bv.z; acc[1][3] += av.y * bv.w;
      acc[2][0] += av.z * bv.x; acc[2][1] += av.z * bv.y; acc[2][2] += av.z * bv.z; acc[2][3] += av.z * bv.w;
      acc[3][0] += av.w * bv.x; acc[3][1] += av.w * bv.y; acc[3][2] += av.w * bv.z; acc[3][3] += av.w * bv.w;
    }
  }
  float* pdst = pout + (size_t)blockIdx.z * (1024 * 384);
  #pragma unroll
  for (int mm = 0; mm < 4; mm++) {
    *(float4*)&pdst[(size_t)(m0 + ty * 4 + mm) * 384 + n0 + tx * 4] =
        make_float4(acc[mm][0], acc[mm][1], acc[mm][2], acc[mm][3]);
  }
}

// ---------------- Kernel 5: split-K reduce + bias ----
__global__ void k_red(const float* __restrict__ pout,
                      const float* __restrict__ bout,
                      float* __restrict__ out) {
  int idx = blockIdx.x * 256 + threadIdx.x;
  const int TOTAL = 1024 * 384;
  float s = pout[idx] + pout[TOTAL + idx] + pout[2 * TOTAL + idx] + pout[3 * TOTAL + idx];
  out[idx] = s + bout[idx % 384];
}

extern "C" void kernel_launch(void* const* d_in, const int* in_sizes, int n_in,
                              void* d_out, int out_size, void* d_ws, size_t ws_size,
                              hipStream_t stream) {
  const float* s_i   = (const float*)d_in[0];
  const float* z     = (const float*)d_in[1];
  const float* rots  = (const float*)d_in[2];
  const float* trans = (const float*)d_in[3];
  const float* wq    = (const float*)d_in[4];
  const float* wk    = (const float*)d_in[5];
  const float* wv    = (const float*)d_in[6];
  const float* wqp   = (const float*)d_in[7];
  const float* wkp   = (const float*)d_in[8];
  const float* wvp   = (const float*)d_in[9];
  const float* wb    = (const float*)d_in[10];
  const float* gamma = (const float*)d_in[11];
  const float* wout  = (const float*)d_in[12];
  const float* bout  = (const float*)d_in[13];
  float* out = (float*)d_out;

  float* ws = (float*)d_ws;
  const size_t TOK = (size_t)BB * NN;  // 1024
  float* qw  = ws;                      // TOK*192
  float* kw  = qw + TOK * 192;
  float* vw  = kw + TOK * 192;
  float* tqw = vw + TOK * 192;          // TOK*144
  float* tkw = tqw + TOK * 144;
  float* tvw = tkw + TOK * 144;         // TOK*288
  float* bw  = tvw + TOK * 288;         // TOK*H*N bias
  float* catm = bw + TOK * HH * NN;     // TOK*2112
  float* pout = catm + TOK * CATW;      // 4*1024*384

  k_proj<<<BB * NN / 2, 256, 0, stream>>>(s_i, rots, trans, wq, wk, wv, wqp, wkp, wvp,
                                          qw, kw, vw, tqw, tkw, tvw);
  k_bias<<<BB * NN * NN / 256, 256, 0, stream>>>(z, wb, bw);
  k_att<<<BB * NN, 256, 0, stream>>>(z, qw, kw, tqw, tkw, vw, tvw, gamma, rots, trans,
                                     bw, catm);
  dim3 gg(6, 16, 4);
  k_gemm<<<gg, 256, 0, stream>>>(catm, wout, pout);
  k_red<<<(1024 * 384) / 256, 256, 0, stream>>>(pout, bout, out);
}

// Round 7
// 902.191 us; speedup vs baseline: 1.0563x; 1.0563x over previous
//
#include <hip/hip_runtime.h>
#include <hip/hip_bf16.h>
#include <math.h>

#define BB 2
#define NN 512
#define CS 384
#define CZ 128
#define HH 12
#define CATW 2112

#define W_L_CONST 0.57735026919f
#define W_C_HALF 0.11785113019f
#define INV_SQRT_D 0.25f
#define LGP 516   // padded row stride for lg[h][*]

// ---------------- Kernel 1: projections + rigid apply (2 tokens/block) ----
// Round-0 structure (8 waves/EU, no occupancy attr) but each task owns 4
// consecutive r -> float4 weight loads (lane-coalesced) + b128 s_row reads.
__global__ void k_proj(const float* __restrict__ s_i,
                       const float* __restrict__ rots,
                       const float* __restrict__ trans,
                       const float* __restrict__ wq,
                       const float* __restrict__ wk,
                       const float* __restrict__ wv,
                       const float* __restrict__ wqp,
                       const float* __restrict__ wkp,
                       const float* __restrict__ wvp,
                       float* __restrict__ qw, float* __restrict__ kw,
                       float* __restrict__ vw, float* __restrict__ tqw,
                       float* __restrict__ tkw, float* __restrict__ tvw) {
  int t0 = blockIdx.x * 2;
  __shared__ __align__(16) float s_row[2][CS];
  __shared__ __align__(16) float praw[2][576];
  __shared__ float R[2][9], T[2][3];
  int tid = threadIdx.x;
  for (int idx = tid; idx < 2 * CS; idx += 256) {
    int tok = idx / CS, c = idx % CS;
    s_row[tok][c] = s_i[(size_t)(t0 + tok) * CS + c];
  }
  if (tid < 18) R[tid / 9][tid % 9] = rots[t0 * 9 + tid];
  if (tid < 6) T[tid / 3][tid % 3] = trans[t0 * 3 + tid];
  __syncthreads();

  // 288 chunks of 4 consecutive outputs; sub-array boundaries are all %4==0.
  for (int ch = tid; ch < 288; ch += 256) {
    int f = ch * 4;
    const float* wp;
    int stride;
    if (f < 576) {
      int sel = f / 192, r = f % 192;
      wp = ((sel == 0) ? wq : (sel == 1) ? wk : wv) + r;
      stride = 192;
    } else {
      int g = f - 576;
      if (g < 144)      { wp = wqp + g;         stride = 144; }
      else if (g < 288) { wp = wkp + (g - 144); stride = 144; }
      else              { wp = wvp + (g - 288); stride = 288; }
    }
    float4 a0 = make_float4(0.f, 0.f, 0.f, 0.f);
    float4 a1 = make_float4(0.f, 0.f, 0.f, 0.f);
    for (int c4 = 0; c4 < 96; c4++) {
      float4 s0 = *(const float4*)&s_row[0][c4 * 4];
      float4 s1 = *(const float4*)&s_row[1][c4 * 4];
      const float* p = wp + (size_t)(c4 * 4) * stride;
      float4 w0 = *(const float4*)p;
      float4 w1 = *(const float4*)(p + stride);
      float4 w2 = *(const float4*)(p + 2 * stride);
      float4 w3 = *(const float4*)(p + 3 * stride);
      a0.x = fmaf(s0.x, w0.x, a0.x); a0.y = fmaf(s0.x, w0.y, a0.y);
      a0.z = fmaf(s0.x, w0.z, a0.z); a0.w = fmaf(s0.x, w0.w, a0.w);
      a1.x = fmaf(s1.x, w0.x, a1.x); a1.y = fmaf(s1.x, w0.y, a1.y);
      a1.z = fmaf(s1.x, w0.z, a1.z); a1.w = fmaf(s1.x, w0.w, a1.w);
      a0.x = fmaf(s0.y, w1.x, a0.x); a0.y = fmaf(s0.y, w1.y, a0.y);
      a0.z = fmaf(s0.y, w1.z, a0.z); a0.w = fmaf(s0.y, w1.w, a0.w);
      a1.x = fmaf(s1.y, w1.x, a1.x); a1.y = fmaf(s1.y, w1.y, a1.y);
      a1.z = fmaf(s1.y, w1.z, a1.z); a1.w = fmaf(s1.y, w1.w, a1.w);
      a0.x = fmaf(s0.z, w2.x, a0.x); a0.y = fmaf(s0.z, w2.y, a0.y);
      a0.z = fmaf(s0.z, w2.z, a0.z); a0.w = fmaf(s0.z, w2.w, a0.w);
      a1.x = fmaf(s1.z, w2.x, a1.x); a1.y = fmaf(s1.z, w2.y, a1.y);
      a1.z = fmaf(s1.z, w2.z, a1.z); a1.w = fmaf(s1.z, w2.w, a1.w);
      a0.x = fmaf(s0.w, w3.x, a0.x); a0.y = fmaf(s0.w, w3.y, a0.y);
      a0.z = fmaf(s0.w, w3.z, a0.z); a0.w = fmaf(s0.w, w3.w, a0.w);
      a1.x = fmaf(s1.w, w3.x, a1.x); a1.y = fmaf(s1.w, w3.y, a1.y);
      a1.z = fmaf(s1.w, w3.z, a1.z); a1.w = fmaf(s1.w, w3.w, a1.w);
    }
    if (f < 576) {
      int sel = f / 192, r = f % 192;
      float* dst = (sel == 0) ? qw : (sel == 1) ? kw : vw;
      *(float4*)&dst[(size_t)(t0 + 0) * 192 + r] = a0;
      *(float4*)&dst[(size_t)(t0 + 1) * 192 + r] = a1;
    } else {
      int g = f - 576;
      *(float4*)&praw[0][g] = a0;
      *(float4*)&praw[1][g] = a1;
    }
  }
  __syncthreads();
  for (int idx = tid; idx < 1152; idx += 256) {
    int tok = idx / 576, f = idx % 576;
    int base, r;
    float* dst;
    if (f < 144)      { r = f;       base = 0;   dst = tqw + (size_t)(t0 + tok) * 144; }
    else if (f < 288) { r = f - 144; base = 144; dst = tkw + (size_t)(t0 + tok) * 144; }
    else              { r = f - 288; base = 288; dst = tvw + (size_t)(t0 + tok) * 288; }
    int hp = r / 3, x = r % 3;
    float v0 = praw[tok][base + hp * 3 + 0];
    float v1 = praw[tok][base + hp * 3 + 1];
    float v2 = praw[tok][base + hp * 3 + 2];
    dst[r] = R[tok][x * 3 + 0] * v0 + R[tok][x * 3 + 1] * v1 + R[tok][x * 3 + 2] * v2 + T[tok][x];
  }
}

// ---------------- Kernel 2: pair bias GEMM (z @ wb), register-cached ------
// Round-6 compute (proven, no spill) + LDS-staged COALESCED output:
// bbs[12][260] then 768 full float4 stores -> kills the 8x write-allocate
// amplification (204.7 MB -> ~25 MB HBM writes).
#define BQ(v, q, sx0, sx1, sx2)                                        \
  sx0 = fmaf(v.x, w[(q)*4 + 0][0], sx0);                               \
  sx1 = fmaf(v.x, w[(q)*4 + 0][1], sx1);                               \
  sx2 = fmaf(v.x, w[(q)*4 + 0][2], sx2);                               \
  sx0 = fmaf(v.y, w[(q)*4 + 1][0], sx0);                               \
  sx1 = fmaf(v.y, w[(q)*4 + 1][1], sx1);                               \
  sx2 = fmaf(v.y, w[(q)*4 + 1][2], sx2);                               \
  sx0 = fmaf(v.z, w[(q)*4 + 2][0], sx0);                               \
  sx1 = fmaf(v.z, w[(q)*4 + 2][1], sx1);                               \
  sx2 = fmaf(v.z, w[(q)*4 + 2][2], sx2);                               \
  sx0 = fmaf(v.w, w[(q)*4 + 3][0], sx0);                               \
  sx1 = fmaf(v.w, w[(q)*4 + 3][1], sx1);                               \
  sx2 = fmaf(v.w, w[(q)*4 + 3][2], sx2);

__global__ void k_bias(const float* __restrict__ z,
                       const float* __restrict__ wb,
                       float* __restrict__ bw) {
  __shared__ __align__(16) float bbs[12][260];
  int tid = threadIdx.x;
  int l32 = tid & 31;
  int grp = tid >> 5;          // 0..7: 32-lane group in block
  int hg = l32 >> 3;           // 0..3: head group (3 heads each)
  int cs = l32 & 7;            // 0..7: c segment (16 c each)

  float w[16][3];
  #pragma unroll
  for (int cc = 0; cc < 16; cc++) {
    const float* p = wb + (size_t)(cs * 16 + cc) * HH + hg * 3;
    w[cc][0] = p[0]; w[cc][1] = p[1]; w[cc][2] = p[2];
  }

  int r0 = blockIdx.x * 256;
  int rloc0 = grp * 32;
  for (int rr = 0; rr < 32; rr += 2) {
    const float* zA = z + (size_t)(r0 + rloc0 + rr) * CZ + cs * 16;
    const float* zB = zA + CZ;
    float4 a0 = ((const float4*)zA)[0];
    float4 a1 = ((const float4*)zA)[1];
    float4 a2 = ((const float4*)zA)[2];
    float4 a3 = ((const float4*)zA)[3];
    float4 b0 = ((const float4*)zB)[0];
    float4 b1 = ((const float4*)zB)[1];
    float4 b2 = ((const float4*)zB)[2];
    float4 b3 = ((const float4*)zB)[3];
    float sA0 = 0.f, sA1 = 0.f, sA2 = 0.f;
    float sB0 = 0.f, sB1 = 0.f, sB2 = 0.f;
    BQ(a0, 0, sA0, sA1, sA2)
    BQ(a1, 1, sA0, sA1, sA2)
    BQ(a2, 2, sA0, sA1, sA2)
    BQ(a3, 3, sA0, sA1, sA2)
    BQ(b0, 0, sB0, sB1, sB2)
    BQ(b1, 1, sB0, sB1, sB2)
    BQ(b2, 2, sB0, sB1, sB2)
    BQ(b3, 3, sB0, sB1, sB2)
    // reduce over cs lanes (lane bits 0..2)
    sA0 += __shfl_xor(sA0, 1, 64); sA0 += __shfl_xor(sA0, 2, 64); sA0 += __shfl_xor(sA0, 4, 64);
    sA1 += __shfl_xor(sA1, 1, 64); sA1 += __shfl_xor(sA1, 2, 64); sA1 += __shfl_xor(sA1, 4, 64);
    sA2 += __shfl_xor(sA2, 1, 64); sA2 += __shfl_xor(sA2, 2, 64); sA2 += __shfl_xor(sA2, 4, 64);
    sB0 += __shfl_xor(sB0, 1, 64); sB0 += __shfl_xor(sB0, 2, 64); sB0 += __shfl_xor(sB0, 4, 64);
    sB1 += __shfl_xor(sB1, 1, 64); sB1 += __shfl_xor(sB1, 2, 64); sB1 += __shfl_xor(sB1, 4, 64);
    sB2 += __shfl_xor(sB2, 1, 64); sB2 += __shfl_xor(sB2, 2, 64); sB2 += __shfl_xor(sB2, 4, 64);
    if (cs == 0) {
      int rl = rloc0 + rr;
      bbs[hg * 3 + 0][rl] = sA0; bbs[hg * 3 + 0][rl + 1] = sB0;
      bbs[hg * 3 + 1][rl] = sA1; bbs[hg * 3 + 1][rl + 1] = sB1;
      bbs[hg * 3 + 2][rl] = sA2; bbs[hg * 3 + 2][rl + 1] = sB2;
    }
  }
  __syncthreads();

  int bi = r0 >> 9;
  int j0 = r0 & 511;
  #pragma unroll
  for (int s = 0; s < 3; s++) {
    int idx = tid + s * 256;              // 768 float4 tasks: [h][64 quads]
    int h = idx >> 6, q4 = (idx & 63) << 2;
    float4 v = *(const float4*)&bbs[h][q4];
    *(float4*)&bw[((size_t)bi * HH + h) * NN + j0 + q4] = v;
  }
}

// ---------------- Kernel 3: fused logits+softmax+o/o_hp+o_hat ------------
// block per (b,i), 256 threads  (round-0 proven version)
__global__ void k_att(const float* __restrict__ z,
                      const float* __restrict__ qw,
                      const float* __restrict__ kw,
                      const float* __restrict__ tqw,
                      const float* __restrict__ tkw,
                      const float* __restrict__ vw,
                      const float* __restrict__ tvw,
                      const float* __restrict__ gamma,
                      const float* __restrict__ rots,
                      const float* __restrict__ trans,
                      const float* __restrict__ bw,
                      float* __restrict__ catm) {
  int bi = blockIdx.x;
  int b = bi / NN;
  __shared__ float lg[HH][LGP];         // logits -> a -> (reused) o_hat partials
  __shared__ float opart[4][480];
  __shared__ float qrow[192], tqrow[144], gam[HH];
  __shared__ float rm[HH][4], rs[HH][4];
  __shared__ float praw[288], ohp[288], R[9], T[3];
  int tid = threadIdx.x;
  int lane = tid & 63, wid = tid >> 6;

  const float* bwrow = bw + (size_t)bi * (HH * NN);
  for (int idx = tid; idx < HH * NN; idx += 256)
    lg[idx >> 9][idx & 511] = bwrow[idx];
  for (int idx = tid; idx < 192; idx += 256) qrow[idx] = qw[(size_t)bi * 192 + idx];
  if (tid < 144) tqrow[tid] = tqw[(size_t)bi * 144 + tid];
  if (tid < HH) gam[tid] = gamma[tid];
  if (tid < 9) R[tid] = rots[bi * 9 + tid];
  if (tid < 3) T[tid] = trans[bi * 3 + tid];
  __syncthreads();

  // ---- logits: 6144 tasks = 24 * 256 ----
  for (int s = 0; s < 24; s++) {
    int task = tid + s * 256;
    int j = task / 12, h = task % 12;
    const float4* kd = (const float4*)(kw + ((size_t)(b * NN + j)) * 192 + h * 16);
    float as = 0.f;
    #pragma unroll
    for (int q = 0; q < 4; q++) {
      float4 kv = kd[q];
      as += qrow[h * 16 + q * 4 + 0] * kv.x + qrow[h * 16 + q * 4 + 1] * kv.y +
            qrow[h * 16 + q * 4 + 2] * kv.z + qrow[h * 16 + q * 4 + 3] * kv.w;
    }
    const float4* td = (const float4*)(tkw + ((size_t)(b * NN + j)) * 144 + h * 12);
    float d2 = 0.f;
    #pragma unroll
    for (int q = 0; q < 3; q++) {
      float4 tv = td[q];
      float d0 = tqrow[h * 12 + q * 4 + 0] - tv.x;
      float d1 = tqrow[h * 12 + q * 4 + 1] - tv.y;
      float d2_ = tqrow[h * 12 + q * 4 + 2] - tv.z;
      float d3 = tqrow[h * 12 + q * 4 + 3] - tv.w;
      d2 += d0 * d0 + d1 * d1 + d2_ * d2_ + d3 * d3;
    }
    lg[h][j] = W_L_CONST * (as * INV_SQRT_D + lg[h][j] - W_C_HALF * gam[h] * d2);
  }
  __syncthreads();

  // ---- softmax ----
  #pragma unroll
  for (int h = 0; h < HH; h++) {
    float m = fmaxf(lg[h][tid], lg[h][tid + 256]);
    #pragma unroll
    for (int off = 32; off >= 1; off >>= 1) m = fmaxf(m, __shfl_xor(m, off, 64));
    if (lane == 0) rm[h][wid] = m;
  }
  __syncthreads();
  #pragma unroll
  for (int h = 0; h < HH; h++) {
    float mx = fmaxf(fmaxf(rm[h][0], rm[h][1]), fmaxf(rm[h][2], rm[h][3]));
    float e0 = __expf(lg[h][tid] - mx);
    float e1 = __expf(lg[h][tid + 256] - mx);
    lg[h][tid] = e0;
    lg[h][tid + 256] = e1;
    float s = e0 + e1;
    #pragma unroll
    for (int off = 32; off >= 1; off >>= 1) s += __shfl_xor(s, off, 64);
    if (lane == 0) rs[h][wid] = s;
  }
  __syncthreads();
  #pragma unroll
  for (int h = 0; h < HH; h++) {
    float inv = 1.0f / (rs[h][0] + rs[h][1] + rs[h][2] + rs[h][3]);
    lg[h][tid] *= inv;
    lg[h][tid + 256] *= inv;
  }
  __syncthreads();   // lg now holds a

  float* crow = catm + (size_t)bi * CATW;
  int j0 = wid * 128;   // this wave's j window

  // ---- o / o_hp partials: wave-split over j ----
  for (int t = lane; t < 480; t += 64) {
    const float* src;
    int h, str;
    if (t < 192) { h = t >> 4; src = vw + (size_t)b * NN * 192 + t; str = 192; }
    else { int f = t - 192; h = f / 24; src = tvw + (size_t)b * NN * 288 + f; str = 288; }
    float sum = 0.f;
    for (int jj = 0; jj < 128; jj += 4) {
      float4 av = *(const float4*)&lg[h][j0 + jj];
      sum += av.x * src[(size_t)(j0 + jj + 0) * str]
           + av.y * src[(size_t)(j0 + jj + 1) * str]
           + av.z * src[(size_t)(j0 + jj + 2) * str]
           + av.w * src[(size_t)(j0 + jj + 3) * str];
    }
    opart[wid][t] = sum;
  }
  __syncthreads();
  for (int t = tid; t < 480; t += 256) {
    float s = opart[0][t] + opart[1][t] + opart[2][t] + opart[3][t];
    if (t < 192) crow[1536 + t] = s;
    else praw[t - 192] = s;
  }
  __syncthreads();
  for (int f = tid; f < 288; f += 256) {
    int g = f / 3, x = f % 3;
    float v0 = praw[g * 3 + 0] - T[0];
    float v1 = praw[g * 3 + 1] - T[1];
    float v2 = praw[g * 3 + 2] - T[2];
    float val = R[0 * 3 + x] * v0 + R[1 * 3 + x] * v1 + R[2 * 3 + x] * v2;
    ohp[f] = val;
    crow[1728 + f] = val;
  }
  __syncthreads();
  if (tid < 96) {
    float x0 = ohp[tid * 3 + 0];
    float x1 = ohp[tid * 3 + 1];
    float x2 = ohp[tid * 3 + 2];
    crow[2016 + tid] = sqrtf(x0 * x0 + x1 * x1 + x2 * x2);
  }

  // ---- o_hat: stream z (second pass), half-wave j-split, float4 c ----
  int hw = lane >> 5, c4 = (lane & 31) * 4;
  float4 acc[HH];
  #pragma unroll
  for (int h = 0; h < HH; h++) acc[h] = make_float4(0.f, 0.f, 0.f, 0.f);
  for (int stp = 0; stp < 64; stp++) {
    int j = j0 + stp * 2 + hw;
    float4 zv = *(const float4*)(z + ((size_t)bi * NN + j) * CZ + c4);
    #pragma unroll
    for (int h = 0; h < HH; h++) {
      float a = lg[h][j];
      acc[h].x += a * zv.x;
      acc[h].y += a * zv.y;
      acc[h].z += a * zv.z;
      acc[h].w += a * zv.w;
    }
  }
  __syncthreads();   // all reads of lg complete everywhere; safe to reuse
  #pragma unroll
  for (int h = 0; h < HH; h++) {
    acc[h].x += __shfl_xor(acc[h].x, 32, 64);
    acc[h].y += __shfl_xor(acc[h].y, 32, 64);
    acc[h].z += __shfl_xor(acc[h].z, 32, 64);
    acc[h].w += __shfl_xor(acc[h].w, 32, 64);
  }
  float* pbuf = &lg[0][0];
  if (lane < 32) {
    #pragma unroll
    for (int h = 0; h < HH; h++)
      *(float4*)&pbuf[wid * 1536 + h * 128 + lane * 4] = acc[h];
  }
  __syncthreads();
  #pragma unroll
  for (int s = 0; s < 6; s++) {
    int idx = tid + s * 256;
    crow[idx] = pbuf[idx] + pbuf[1536 + idx] + pbuf[3072 + idx] + pbuf[4608 + idx];
  }
}

// ---------------- Kernel 4: output GEMM, split-K=4, 64x64, 4x4 reg tile ---
#define KCH 528
__global__ void k_gemm(const float* __restrict__ catm,
                       const float* __restrict__ wout,
                       float* __restrict__ pout) {
  __shared__ float As[16][68];   // [kk][m], padded
  __shared__ float Bs[16][64];   // [kk][n]
  int tid = threadIdx.x;
  int n0 = blockIdx.x * 64, m0 = blockIdx.y * 64, kbase = blockIdx.z * KCH;
  int tx = tid & 15, ty = tid >> 4;
  int sm = tid & 63, skk4 = tid >> 6;
  int bkk = tid >> 4, bn4 = (tid & 15) * 4;
  float acc[4][4] = {};
  for (int kt = 0; kt < KCH / 16; kt++) {
    int k0 = kbase + kt * 16;
    float4 ga = *(const float4*)(catm + (size_t)(m0 + sm) * CATW + k0 + skk4 * 4);
    float4 gb = *(const float4*)(wout + (size_t)(k0 + bkk) * 384 + n0 + bn4);
    __syncthreads();
    As[skk4 * 4 + 0][sm] = ga.x;
    As[skk4 * 4 + 1][sm] = ga.y;
    As[skk4 * 4 + 2][sm] = ga.z;
    As[skk4 * 4 + 3][sm] = ga.w;
    *(float4*)&Bs[bkk][bn4] = gb;
    __syncthreads();
    #pragma unroll
    for (int kk = 0; kk < 16; kk++) {
      float4 av = *(const float4*)&As[kk][ty * 4];
      float4 bv = *(const float4*)&Bs[kk][tx * 4];
      acc[0][0] += av.x * bv.x; acc[0][1] += av.x * bv.y; acc[0][2] += av.x * bv.z; acc[0][3] += av.x * bv.w;
      acc[1][0] += av.y * bv.x; acc[1][1] += av.y * bv.y; acc[1][2] += av.y * bv.z; acc[1][3] += av.y * bv.w;
      acc[2][0] += av.z * bv.x; acc[2][1] += av.z * bv.y; acc[2][2] += av.z * bv.z; acc[2][3] += av.z * bv.w;
      acc[3][0] += av.w * bv.x; acc[3][1] += av.w * bv.y; acc[3][2] += av.w * bv.z; acc[3][3] += av.w * bv.w;
    }
  }
  float* pdst = pout + (size_t)blockIdx.z * (1024 * 384);
  #pragma unroll
  for (int mm = 0; mm < 4; mm++) {
    *(float4*)&pdst[(size_t)(m0 + ty * 4 + mm) * 384 + n0 + tx * 4] =
        make_float4(acc[mm][0], acc[mm][1], acc[mm][2], acc[mm][3]);
  }
}

// ---------------- Kernel 5: split-K reduce + bias ----
__global__ void k_red(const float* __restrict__ pout,
                      const float* __restrict__ bout,
                      float* __restrict__ out) {
  int idx = blockIdx.x * 256 + threadIdx.x;
  const int TOTAL = 1024 * 384;
  float s = pout[idx] + pout[TOTAL + idx] + pout[2 * TOTAL + idx] + pout[3 * TOTAL + idx];
  out[idx] = s + bout[idx % 384];
}

extern "C" void kernel_launch(void* const* d_in, const int* in_sizes, int n_in,
                              void* d_out, int out_size, void* d_ws, size_t ws_size,
                              hipStream_t stream) {
  const float* s_i   = (const float*)d_in[0];
  const float* z     = (const float*)d_in[1];
  const float* rots  = (const float*)d_in[2];
  const float* trans = (const float*)d_in[3];
  const float* wq    = (const float*)d_in[4];
  const float* wk    = (const float*)d_in[5];
  const float* wv    = (const float*)d_in[6];
  const float* wqp   = (const float*)d_in[7];
  const float* wkp   = (const float*)d_in[8];
  const float* wvp   = (const float*)d_in[9];
  const float* wb    = (const float*)d_in[10];
  const float* gamma = (const float*)d_in[11];
  const float* wout  = (const float*)d_in[12];
  const float* bout  = (const float*)d_in[13];
  float* out = (float*)d_out;

  float* ws = (float*)d_ws;
  const size_t TOK = (size_t)BB * NN;  // 1024
  float* qw  = ws;                      // TOK*192
  float* kw  = qw + TOK * 192;
  float* vw  = kw + TOK * 192;
  float* tqw = vw + TOK * 192;          // TOK*144
  float* tkw = tqw + TOK * 144;
  float* tvw = tkw + TOK * 144;         // TOK*288
  float* bw  = tvw + TOK * 288;         // TOK*H*N bias
  float* catm = bw + TOK * HH * NN;     // TOK*2112
  float* pout = catm + TOK * CATW;      // 4*1024*384

  k_proj<<<BB * NN / 2, 256, 0, stream>>>(s_i, rots, trans, wq, wk, wv, wqp, wkp, wvp,
                                          qw, kw, vw, tqw, tkw, tvw);
  k_bias<<<BB * NN * NN / 256, 256, 0, stream>>>(z, wb, bw);
  k_att<<<BB * NN, 256, 0, stream>>>(z, qw, kw, tqw, tkw, vw, tvw, gamma, rots, trans,
                                     bw, catm);
  dim3 gg(6, 16, 4);
  k_gemm<<<gg, 256, 0, stream>>>(catm, wout, pout);
  k_red<<<(1024 * 384) / 256, 256, 0, stream>>>(pout, bout, out);
}